// Round 11
// baseline (83.260 us; speedup 1.0000x reference)
//
#include <hip/hip_runtime.h>

// Fused upfirdn2d: up2(FIR12,H) -> up2(FIR12,W) -> +bias -> lrelu*sqrt2
//                  -> down2(FIR12,H) -> down2(FIR12,W)
// x: (32,128,64,64) f32.
// R11 = R10 quarter-slice skeleton + R7's merged upW+lrelu+downW phase.
//   Pipe accounting showed R10's LDS pipe ~87% busy (140 wave-b128/block
//   x 8cy + conflicts ~= runtime). The y[42][148] buffer round-trip was
//   55% of that. Merged phase: 6 reads -> 26 y in regs -> 8 yw outputs ->
//   2 writes; y buffer deleted. LDS/block 39KB -> 25.5KB, instrs 140 -> ~84.
//   VALU becomes the binding pipe (y-recompute overlap tax ~1.6x on upW).
//
// Index math:
//   z[i][c]  = sum_{j == i (mod 2)} (2*fu[j]) * x[(i-j)/2][c]
//   y[i][w]  = sum_{j == w (mod 2)} (2*fu[j]) * z[i][(w-j)/2]; lrelu(y+b)*g
//   yw[i][p] = sum_{j} fd[j] * y[i][2p+11-j]          (down-W; commutes w/ down-H)
//   out[o][p]= sum_{j} fd[j] * yw[2o+11-j][p]         (down-H)

#define NT 512
#define GAIN 1.41421356237309504880f
#define C1 (0.6f * GAIN)
#define C2 (0.4f * GAIN)

#define ZROWS 42              // quarter: out rows [o0,o0+16) -> z/yw rows [2o0,2o0+42)
#define ZSTRIDE 84            // 336B = 80B mod 128 -> full rotation, row-walk
#define ZPAD 8                // local col p <-> real z col p-8 ; pads zeroed
#define YWSTRIDE 68           // 272B = 16B mod 128 -> full rotation, row-walk

#define ZB_OFF 0
#define YW_OFF (ZROWS * ZSTRIDE)               // 3528
#define LDS_FLOATS (YW_OFF + ZROWS * YWSTRIDE) // 6384 floats = 25536 B

// wave-uniform float -> SGPR
__device__ __forceinline__ float sload(float v) {
    return __uint_as_float(__builtin_amdgcn_readfirstlane(__float_as_uint(v)));
}

__global__ __launch_bounds__(NT, 8) void fused_upfirdn_lrelu(
    const float* __restrict__ x,
    const float* __restrict__ bias,
    const float* __restrict__ upf,
    const float* __restrict__ dnf,
    float* __restrict__ out)
{
    extern __shared__ float lds[];
    float* zb = lds + ZB_OFF;
    float* yw = lds + YW_OFF;

    const int t = threadIdx.x;
    const int bid = blockIdx.x;
    const int s = bid >> 2;           // slice = n*128 + c
    const int o0 = (bid & 3) << 4;    // 0,16,32,48
    const int c = s & 127;

    // filters + bias in SGPRs (uniform); fu pre-scaled by UP=2
    float fu[12], fd[12];
#pragma unroll
    for (int j = 0; j < 12; ++j) {
        fu[j] = sload(2.0f * upf[j]);
        fd[j] = sload(dnf[j]);
    }
    const float bv = sload(bias[c]);

    const float* xg = x + (size_t)s * 4096;
    float* outg = out + (size_t)s * 4096;

    // ---- P1: up-H from GLOBAL x -> z local rows [0,42).  t<336: task=(m,c4),
    //      z rows 2m,2m+1 from x rows M-5..M (M=o0+m), interior unchecked.
    //      t>=336: zero z pad cols [0,8) and [72,84). ----
    if (t < 336) {
        const int m = t >> 4;                 // 0..20
        const int c4 = (t & 15) << 2;
        const int M = o0 + m;
        float4 xv[6];
        if (M >= 5 && M <= 63) {              // interior: no bounds checks
#pragma unroll
            for (int d = 0; d < 6; ++d)
                xv[d] = *reinterpret_cast<const float4*>(xg + (M - 5 + d) * 64 + c4);
        } else {
#pragma unroll
            for (int d = 0; d < 6; ++d) {
                const int r = M - 5 + d;
                xv[d] = (r >= 0 && r <= 63)
                      ? *reinterpret_cast<const float4*>(xg + r * 64 + c4)
                      : make_float4(0.f, 0.f, 0.f, 0.f);
            }
        }
        float a0[4] = {0,0,0,0}, a1[4] = {0,0,0,0};
#pragma unroll
        for (int d = 0; d < 6; ++d) {         // tt = 5-d
            const float w0 = fu[2 * (5 - d)], w1 = fu[2 * (5 - d) + 1];
            a0[0] += w0 * xv[d].x; a0[1] += w0 * xv[d].y; a0[2] += w0 * xv[d].z; a0[3] += w0 * xv[d].w;
            a1[0] += w1 * xv[d].x; a1[1] += w1 * xv[d].y; a1[2] += w1 * xv[d].z; a1[3] += w1 * xv[d].w;
        }
        float* zr = zb + (2 * m) * ZSTRIDE + ZPAD + c4;
        *reinterpret_cast<float4*>(zr)           = make_float4(a0[0], a0[1], a0[2], a0[3]);
        *reinterpret_cast<float4*>(zr + ZSTRIDE) = make_float4(a1[0], a1[1], a1[2], a1[3]);
    } else {
        // 5 float4 pad-writes per row x 42 rows = 210 tasks over 176 threads
        for (int pt = t - 336; pt < 210; pt += 176) {
            const int rl = pt / 5;
            const int p = pt - rl * 5;
            const int col = (p < 2) ? (p << 2) : (72 + ((p - 2) << 2));
            *reinterpret_cast<float4*>(zb + rl * ZSTRIDE + col) = make_float4(0.f, 0.f, 0.f, 0.f);
        }
    }
    __syncthreads();

    // ---- P2 (merged upW+lrelu+downW): task=(cg, il), groups of 48 (mult of 8),
    //      il fast-varying (336B lane stride -> bank-clean).  Per task:
    //      6 b128 z-reads -> 26 y values computed in regs (immediately folded
    //      into acc[8], never materialized) -> 2 b128 yw writes. ----
    if (t < 384) {
        const int cg = t / 48;                // 0..7 ; outputs p = 8cg..8cg+7
        const int il = t - cg * 48;
        if (il < ZROWS) {
            const float* zr = zb + il * ZSTRIDE + (cg << 3);   // local col 8cg = real 8cg-8
            float zv[24];
#pragma unroll
            for (int q = 0; q < 6; ++q) {
                const float4 v = *reinterpret_cast<const float4*>(zr + (q << 2));
                zv[4 * q] = v.x; zv[4 * q + 1] = v.y; zv[4 * q + 2] = v.z; zv[4 * q + 3] = v.w;
            }
            float acc[8] = {0, 0, 0, 0, 0, 0, 0, 0};
#pragma unroll
            for (int v = 0; v < 13; ++v) {    // y[u=2v], y[u=2v+1]; w = 16cg+u
                float a0 = bv, a1 = bv;
#pragma unroll
                for (int tt = 0; tt < 6; ++tt) {
                    const float zz = zv[v + 8 - tt];
                    a0 += fu[2 * tt]     * zz;
                    a1 += fu[2 * tt + 1] * zz;
                }
                const float y0 = C1 * a0 + C2 * fabsf(a0);   // g*lrelu
                const float y1 = C1 * a1 + C2 * fabsf(a1);
                // y[u] -> acc[e] with tap j = 2e+11-u (compile-time per (v,e))
#pragma unroll
                for (int e = 0; e < 8; ++e) {
                    const int j0 = 2 * e + 11 - 2 * v;       // u = 2v
                    const int j1 = 2 * e + 10 - 2 * v;       // u = 2v+1
                    if (j0 >= 0 && j0 <= 11) acc[e] += fd[j0] * y0;
                    if (j1 >= 0 && j1 <= 11) acc[e] += fd[j1] * y1;
                }
            }
            float* wr = yw + il * YWSTRIDE + (cg << 3);
            *reinterpret_cast<float4*>(wr)     = make_float4(acc[0], acc[1], acc[2], acc[3]);
            *reinterpret_cast<float4*>(wr + 4) = make_float4(acc[4], acc[5], acc[6], acc[7]);
        }
    }
    __syncthreads();

    // ---- P3: down-H on yw -> GLOBAL out.  t<64: task=(eg, col4): 4 out rows
    //      x 4 cols from 18 yw rows (1.125 reads/output); col4 fast-varying
    //      -> 128B-contiguous 8-lane groups, bank-clean. ----
    if (t < 64) {
        const int eg = t >> 4;                // 0..3 ; out rows o0+4eg..o0+4eg+3
        const int col4 = (t & 15) << 2;       // 0..60
        const float* wr = yw + (eg << 3) * YWSTRIDE + col4;    // yw rows 8eg..8eg+17
        float acc[4][4] = {{0,0,0,0},{0,0,0,0},{0,0,0,0},{0,0,0,0}};
#pragma unroll
        for (int r = 0; r < 18; ++r) {
            const float4 v = *reinterpret_cast<const float4*>(wr + r * YWSTRIDE);
#pragma unroll
            for (int e = 0; e < 4; ++e) {
                if (r >= 2 * e && r <= 2 * e + 11) {           // compile-time per (r,e)
                    const float ww = fd[11 - r + 2 * e];
                    acc[e][0] += ww * v.x; acc[e][1] += ww * v.y;
                    acc[e][2] += ww * v.z; acc[e][3] += ww * v.w;
                }
            }
        }
#pragma unroll
        for (int e = 0; e < 4; ++e)
            *reinterpret_cast<float4*>(outg + (o0 + (eg << 2) + e) * 64 + col4) =
                make_float4(acc[e][0], acc[e][1], acc[e][2], acc[e][3]);
    }
}

extern "C" void kernel_launch(void* const* d_in, const int* in_sizes, int n_in,
                              void* d_out, int out_size, void* d_ws, size_t ws_size,
                              hipStream_t stream) {
    const float* x    = (const float*)d_in[0];
    const float* bias = (const float*)d_in[1];
    const float* upf  = (const float*)d_in[2];
    const float* dnf  = (const float*)d_in[3];
    float* out = (float*)d_out;

    const int n_blocks = 32 * 128 * 4;   // four quarter-slices per (n,c)
    const size_t lds_bytes = (size_t)LDS_FLOATS * sizeof(float);
    hipLaunchKernelGGL(fused_upfirdn_lrelu, dim3(n_blocks), dim3(NT),
                       lds_bytes, stream, x, bias, upf, dnf, out);
}

// Round 12
// 77.772 us; speedup vs baseline: 1.0706x; 1.0706x over previous
//
#include <hip/hip_runtime.h>

// Fused upfirdn2d: up2(FIR12,H) -> up2(FIR12,W) -> +bias -> lrelu*sqrt2
//                  -> down2(FIR12,H) -> down2(FIR12,W)
// x: (32,128,64,64) f32.
// R12: ONE-BARRIER WAVE-LOCAL PIPELINE (quarter-slice, NT=448 = 7 waves).
//   upW and downW are ROW-LOCAL: y/yw row il depends only on z/y row il.
//   Wave w owns m in {3w,3w+1,3w+2} -> z/y/yw rows 6w..6w+5. P1->P2->P3 are
//   intra-wave (same-wave DS ops are in-order; no __syncthreads needed).
//   ONE barrier before P4 (downH crosses rows). 7-wave blocks pack 4/CU
//   (28/32 wave slots). yw aliases own z rows (dead after own P2). 39KB LDS.
//   R5..R11 data: separate phases are FLOP-minimal; plateau 73-75us with
//   VALU~60%/LDS~60% and conflict cuts not helping -> barrier-bubble theory.
//
// Index math:
//   z[i][c]  = sum_{j == i (mod 2)} (2*fu[j]) * x[(i-j)/2][c]
//   y[i][w]  = sum_{j == w (mod 2)} (2*fu[j]) * z[i][(w-j)/2]; lrelu(y+b)*g
//   yw[i][p] = sum_{j} fd[j] * y[i][2p+11-j]          (down-W; commutes w/ down-H)
//   out[o][p]= sum_{j} fd[j] * yw[2o+11-j][p]         (down-H)

#define NT 448
#define GAIN 1.41421356237309504880f
#define C1 (0.6f * GAIN)
#define C2 (0.4f * GAIN)

#define ZROWS 42              // quarter: out rows [o0,o0+16) -> z/y/yw rows [2o0,2o0+42)
#define ZSTRIDE 84            // 336B = 80B mod 128 -> full rotation, row-walk
#define ZPAD 8                // local col p <-> real z col p-8 ; pads zeroed
#define YSTRIDE 148           // 592B = 80B mod 128 -> full rotation, row-walk
#define YWSTRIDE 84           // yw aliases zb rows (stride 84), cols [0,68)

#define ZB_OFF 0
#define YB_OFF (ZROWS * ZSTRIDE)              // 3528
#define LDS_FLOATS (YB_OFF + ZROWS * YSTRIDE) // 9744 floats = 38976 B -> 4 blk/CU

// wave-uniform float -> SGPR
__device__ __forceinline__ float sload(float v) {
    return __uint_as_float(__builtin_amdgcn_readfirstlane(__float_as_uint(v)));
}

__global__ __launch_bounds__(NT, 7) void fused_upfirdn_lrelu(
    const float* __restrict__ x,
    const float* __restrict__ bias,
    const float* __restrict__ upf,
    const float* __restrict__ dnf,
    float* __restrict__ out)
{
    extern __shared__ float lds[];
    float* zb = lds + ZB_OFF;     // z[42][84]; later aliased as yw rows
    float* yb = lds + YB_OFF;     // y[42][148]

    const int t = threadIdx.x;
    const int w = t >> 6;             // wave 0..6 ; owns rows 6w..6w+5
    const int l = t & 63;
    const int bid = blockIdx.x;
    const int s = bid >> 2;           // slice = n*128 + c
    const int o0 = (bid & 3) << 4;    // 0,16,32,48
    const int c = s & 127;

    // filters + bias in SGPRs (uniform); fu pre-scaled by UP=2
    float fu[12], fd[12];
#pragma unroll
    for (int j = 0; j < 12; ++j) {
        fu[j] = sload(2.0f * upf[j]);
        fd[j] = sload(dnf[j]);
    }
    const float bv = sload(bias[c]);

    const float* xg = x + (size_t)s * 4096;
    float* outg = out + (size_t)s * 4096;

    // ---- P1 (wave-local): up-H from GLOBAL x -> z rows 6w..6w+5.
    //      Lanes 0..47: (ml,c4): m = 3w+ml, z rows 2m,2m+1 from x rows M-5..M.
    //      Lanes 48..63: zero own rows' pad cols [0,8) and [72,80). ----
    if (l < 48) {
        const int ml = l >> 4;                // 0..2
        const int c4 = (l & 15) << 2;
        const int m = 3 * w + ml;             // 0..20
        const int M = o0 + m;
        float4 xv[6];
        if (M >= 5 && M <= 63) {              // interior: no bounds checks
#pragma unroll
            for (int d = 0; d < 6; ++d)
                xv[d] = *reinterpret_cast<const float4*>(xg + (M - 5 + d) * 64 + c4);
        } else {
#pragma unroll
            for (int d = 0; d < 6; ++d) {
                const int r = M - 5 + d;
                xv[d] = (r >= 0 && r <= 63)
                      ? *reinterpret_cast<const float4*>(xg + r * 64 + c4)
                      : make_float4(0.f, 0.f, 0.f, 0.f);
            }
        }
        float a0[4] = {0,0,0,0}, a1[4] = {0,0,0,0};
#pragma unroll
        for (int d = 0; d < 6; ++d) {         // tt = 5-d
            const float w0 = fu[2 * (5 - d)], w1 = fu[2 * (5 - d) + 1];
            a0[0] += w0 * xv[d].x; a0[1] += w0 * xv[d].y; a0[2] += w0 * xv[d].z; a0[3] += w0 * xv[d].w;
            a1[0] += w1 * xv[d].x; a1[1] += w1 * xv[d].y; a1[2] += w1 * xv[d].z; a1[3] += w1 * xv[d].w;
        }
        float* zr = zb + (2 * m) * ZSTRIDE + ZPAD + c4;
        *reinterpret_cast<float4*>(zr)           = make_float4(a0[0], a0[1], a0[2], a0[3]);
        *reinterpret_cast<float4*>(zr + ZSTRIDE) = make_float4(a1[0], a1[1], a1[2], a1[3]);
    } else {
        // 6 rows x 4 pad-float4 = 24 tasks over 16 lanes
        for (int pi = l - 48; pi < 24; pi += 16) {
            const int rl = pi >> 2;           // 0..5
            const int pp = pi & 3;            // 0..3 -> cols 0,4,72,76
            const int col = (pp < 2) ? (pp << 2) : (64 + ((pp - 2) << 2) + 8);
            *reinterpret_cast<float4*>(zb + (6 * w + rl) * ZSTRIDE + col) =
                make_float4(0.f, 0.f, 0.f, 0.f);
        }
    }
    // no barrier: same-wave DS ops are in-order

    // ---- P2 (wave-local): up-W + bias + lrelu on OWN rows -> y[il][148].
    //      Lanes 0..53: cg = l/6 (0..8), il = 6w + l%6. ----
    if (l < 54) {
        const int cg = l / 6;
        const int il = 6 * w + (l - cg * 6);
        const int mbase = cg << 3;
        const float* zr = zb + il * ZSTRIDE + mbase;   // local col = real col + 8
        float zv[16];
#pragma unroll
        for (int q = 0; q < 4; ++q) {
            const float4 v = *reinterpret_cast<const float4*>(zr + (q << 2));
            zv[4 * q] = v.x; zv[4 * q + 1] = v.y; zv[4 * q + 2] = v.z; zv[4 * q + 3] = v.w;
        }
        float yv[16];
#pragma unroll
        for (int e = 0; e < 8; ++e) {         // m = mbase+e -> w-cols 2m, 2m+1
            float a0 = bv, a1 = bv;
#pragma unroll
            for (int tt = 0; tt < 6; ++tt) {
                const float zz = zv[8 + e - tt];
                a0 += fu[2 * tt]     * zz;
                a1 += fu[2 * tt + 1] * zz;
            }
            yv[2 * e]     = C1 * a0 + C2 * fabsf(a0);   // g*lrelu
            yv[2 * e + 1] = C1 * a1 + C2 * fabsf(a1);
        }
        float* yr = yb + il * YSTRIDE + (mbase << 1);
#pragma unroll
        for (int q = 0; q < 4; ++q)
            *reinterpret_cast<float4*>(yr + (q << 2)) =
                make_float4(yv[4 * q], yv[4 * q + 1], yv[4 * q + 2], yv[4 * q + 3]);
    }
    // no barrier

    // ---- P3 (wave-local): down-W on OWN rows -> yw row il, ALIASED into
    //      own z row il (dead after own P2).  Lanes 0..47: cg 0..7, il own. ----
    if (l < 48) {
        const int cg = l / 6;
        const int il = 6 * w + (l - cg * 6);
        const float* yr = yb + il * YSTRIDE + (cg << 4);   // y cols 16cg..16cg+27
        float wv[28];
#pragma unroll
        for (int q = 0; q < 7; ++q) {
            const float4 v = *reinterpret_cast<const float4*>(yr + (q << 2));
            wv[4 * q] = v.x; wv[4 * q + 1] = v.y; wv[4 * q + 2] = v.z; wv[4 * q + 3] = v.w;
        }
        float rv[8];
#pragma unroll
        for (int e = 0; e < 8; ++e) {         // p = 8cg+e : y cols 2p..2p+11
            float a = 0.0f;
#pragma unroll
            for (int j = 0; j < 12; ++j) a += fd[j] * wv[2 * e + 11 - j];
            rv[e] = a;
        }
        float* wr = zb + il * YWSTRIDE + (cg << 3);        // yw aliases zb
        *reinterpret_cast<float4*>(wr)     = make_float4(rv[0], rv[1], rv[2], rv[3]);
        *reinterpret_cast<float4*>(wr + 4) = make_float4(rv[4], rv[5], rv[6], rv[7]);
    }

    __syncthreads();   // the ONLY barrier: down-H crosses wave row-strips

    // ---- P4: down-H on yw(=zb) -> GLOBAL out.  t<128 (waves 0-1):
    //      task=(eg, col4): 2 out rows x 4 cols from 14 yw rows. ----
    if (t < 128) {
        const int eg = t >> 4;                // 0..7 ; out rows o0+2eg, o0+2eg+1
        const int col4 = (t & 15) << 2;       // 0..60
        const float* wr = zb + (eg << 2) * YWSTRIDE + col4;   // yw rows 4eg..4eg+13
        float aA[4] = {0,0,0,0}, aB[4] = {0,0,0,0};
#pragma unroll
        for (int r = 0; r < 14; ++r) {
            const float4 v = *reinterpret_cast<const float4*>(wr + r * YWSTRIDE);
            if (r < 12) {                     // row A taps: j = 11-r
                const float ww = fd[11 - r];
                aA[0] += ww * v.x; aA[1] += ww * v.y; aA[2] += ww * v.z; aA[3] += ww * v.w;
            }
            if (r >= 2) {                     // row B taps: j = 13-r
                const float ww = fd[13 - r];
                aB[0] += ww * v.x; aB[1] += ww * v.y; aB[2] += ww * v.z; aB[3] += ww * v.w;
            }
        }
        float* orow = outg + (o0 + (eg << 1)) * 64 + col4;
        *reinterpret_cast<float4*>(orow)      = make_float4(aA[0], aA[1], aA[2], aA[3]);
        *reinterpret_cast<float4*>(orow + 64) = make_float4(aB[0], aB[1], aB[2], aB[3]);
    }
}

extern "C" void kernel_launch(void* const* d_in, const int* in_sizes, int n_in,
                              void* d_out, int out_size, void* d_ws, size_t ws_size,
                              hipStream_t stream) {
    const float* x    = (const float*)d_in[0];
    const float* bias = (const float*)d_in[1];
    const float* upf  = (const float*)d_in[2];
    const float* dnf  = (const float*)d_in[3];
    float* out = (float*)d_out;

    const int n_blocks = 32 * 128 * 4;   // four quarter-slices per (n,c)
    const size_t lds_bytes = (size_t)LDS_FLOATS * sizeof(float);
    hipLaunchKernelGGL(fused_upfirdn_lrelu, dim3(n_blocks), dim3(NT),
                       lds_bytes, stream, x, bias, upf, dnf, out);
}